// Round 1
// baseline (3677.636 us; speedup 1.0000x reference)
//
#include <hip/hip_runtime.h>

#define NATOMS 400000
#define NEDGES 800000
#define NMOLS  13000
#define AF 133
#define BFdim 14
#define BFD 147

typedef __attribute__((ext_vector_type(8))) short  s16x8;
typedef __attribute__((ext_vector_type(8))) __bf16 b16x8;
typedef __attribute__((ext_vector_type(4))) float  f32x4;

__device__ __forceinline__ float bf2f(unsigned short u){
  union { unsigned int i; float f; } v; v.i = ((unsigned int)u) << 16; return v.f;
}
__device__ __forceinline__ unsigned short f2bf(float f){
  union { float ff; unsigned int i; } v; v.ff = f;
  unsigned int b = v.i + 0x7fffu + ((v.i >> 16) & 1u);
  return (unsigned short)(b >> 16);
}
__device__ __forceinline__ f32x4 mfma16(s16x8 a, s16x8 b, f32x4 c){
  return __builtin_amdgcn_mfma_f32_16x16x32_bf16(
      __builtin_bit_cast(b16x8, a), __builtin_bit_cast(b16x8, b), c, 0, 0, 0);
}

// ---------------- weight prep: fp32 -> bf16 fragment order ----------------
// frag layout: element (fi, lane, j) at dst[fi*512 + lane*8 + j] holds
// src[k][n], k = kb*32 + (lane>>4)*8 + j, n = nb*16 + (lane&15), fi = nb*KB+kb
__global__ void k_prep_weights(const float* __restrict__ W_i, const float* __restrict__ W_h,
                               const float* __restrict__ W_o, const float* __restrict__ node_W,
                               const float* __restrict__ edge_W,
                               ushort* __restrict__ Wif, ushort* __restrict__ Wof1,
                               ushort* __restrict__ Whf, ushort* __restrict__ Wof2,
                               ushort* __restrict__ nWf, ushort* __restrict__ eWf){
  int gid = blockIdx.x * 256 + threadIdx.x;
  ushort* dst; const float* src; int KB, Kv, Ns, idx;
  if      (gid <  40960){ idx = gid;          dst = Wif;  src = W_i;          KB = 5; Kv = 147; Ns = 256; }
  else if (gid <  81920){ idx = gid -  40960; dst = Wof1; src = W_o;          KB = 5; Kv = 133; Ns = 256; }
  else if (gid < 147456){ idx = gid -  81920; dst = Whf;  src = W_h;          KB = 8; Kv = 256; Ns = 256; }
  else if (gid < 212992){ idx = gid - 147456; dst = Wof2; src = W_o + 133*256;KB = 8; Kv = 256; Ns = 256; }
  else if (gid < 249856){ idx = gid - 212992; dst = nWf;  src = node_W;       KB = 8; Kv = 256; Ns = 133; }
  else if (gid < 253952){ idx = gid - 249856; dst = eWf;  src = edge_W;       KB = 8; Kv = 256; Ns = 14;  }
  else return;
  int j = idx & 7, lane = (idx >> 3) & 63, fi = idx >> 9;
  int kb = fi % KB, nb = fi / KB;
  int k = kb * 32 + ((lane >> 4) << 3) + j;
  int n = nb * 16 + (lane & 15);
  float v = 0.f;
  if (k < Kv && n < Ns) v = src[(size_t)k * Ns + n];
  dst[idx] = f2bf(v);
}

// ---------------- CSR build over dst ----------------
__global__ void k_hist(const int* __restrict__ dsti, int* __restrict__ deg){
  int e = blockIdx.x * 256 + threadIdx.x;
  if (e < NEDGES) atomicAdd(&deg[dsti[e]], 1);
}
__global__ void k_blocksum(const int* __restrict__ deg, int* __restrict__ bsum){
  __shared__ int s[256];
  int i = blockIdx.x * 256 + threadIdx.x;
  s[threadIdx.x] = (i < NATOMS) ? deg[i] : 0;
  __syncthreads();
  for (int st = 128; st > 0; st >>= 1){
    if (threadIdx.x < st) s[threadIdx.x] += s[threadIdx.x + st];
    __syncthreads();
  }
  if (threadIdx.x == 0) bsum[blockIdx.x] = s[0];
}
#define NBLK 1563
__global__ void k_scanblk(const int* __restrict__ bs, int* __restrict__ bo){
  __shared__ int s[2048];
  int t = threadIdx.x;
  s[2*t]   = (2*t   < NBLK) ? bs[2*t]   : 0;
  s[2*t+1] = (2*t+1 < NBLK) ? bs[2*t+1] : 0;
  int offset = 1;
  for (int d = 1024; d > 0; d >>= 1){
    __syncthreads();
    if (t < d){ int ai = offset*(2*t+1)-1, bi = offset*(2*t+2)-1; s[bi] += s[ai]; }
    offset <<= 1;
  }
  __syncthreads();
  if (t == 0) s[2047] = 0;
  for (int d = 1; d < 2048; d <<= 1){
    offset >>= 1;
    __syncthreads();
    if (t < d){ int ai = offset*(2*t+1)-1, bi = offset*(2*t+2)-1;
                int tmp = s[ai]; s[ai] = s[bi]; s[bi] += tmp; }
  }
  __syncthreads();
  if (2*t   < NBLK) bo[2*t]   = s[2*t];
  if (2*t+1 < NBLK) bo[2*t+1] = s[2*t+1];
}
__global__ void k_offs(const int* __restrict__ deg, const int* __restrict__ bo,
                       int* __restrict__ offs, int* __restrict__ cursor){
  __shared__ int s1[256], s2[256];
  int t = threadIdx.x;
  int i = blockIdx.x * 256 + t;
  int v = (i < NATOMS) ? deg[i] : 0;
  s1[t] = v;
  __syncthreads();
  int* rd = s1; int* wr = s2;
  for (int ofs = 1; ofs < 256; ofs <<= 1){
    wr[t] = rd[t] + ((t >= ofs) ? rd[t - ofs] : 0);
    __syncthreads();
    int* tmp = rd; rd = wr; wr = tmp;
  }
  if (i < NATOMS){
    int excl = rd[t] - v + bo[blockIdx.x];
    offs[i] = excl; cursor[i] = excl;
  }
  if (i == 0) offs[NATOMS] = NEDGES;
}
__global__ void k_fill(const int* __restrict__ dsti, int* __restrict__ cursor,
                       int* __restrict__ elist){
  int e = blockIdx.x * 256 + threadIdx.x;
  if (e < NEDGES){ int pos = atomicAdd(&cursor[dsti[e]], 1); elist[pos] = e; }
}
__global__ void k_molstart(const int* __restrict__ atom_mol, int* __restrict__ molst){
  int m = blockIdx.x * 256 + threadIdx.x;
  if (m > NMOLS) return;
  int lo = 0, hi = NATOMS;
  while (lo < hi){ int mid = (lo + hi) >> 1; if (atom_mol[mid] < m) lo = mid + 1; else hi = mid; }
  molst[m] = lo;
}

// ---------------- skinny-K GEMM (K padded to 160): f32 rows -> bf16 out ----------------
// out_pre = A @ B ; out_relu = relu(same). Either may be null.
__global__ __launch_bounds__(256) void k_skinny(
    const float* __restrict__ A, int rowlen,
    const ushort* __restrict__ Bf,
    ushort* __restrict__ out_pre, ushort* __restrict__ out_relu){
  __shared__ ushort At[64 * 192]; // pitch 384B, XOR-swizzled
  const int t = threadIdx.x;
  const long r0 = (long)blockIdx.x * 64;
  {
    const int r = t >> 2, q = t & 3;
    const float* ap = A + (r0 + r) * rowlen;
    #pragma unroll 8
    for (int jj = 0; jj < 40; jj++){
      int c = q + (jj << 2);
      float v = (c < rowlen) ? ap[c] : 0.f;
      int byte = r * 384 + ((c * 2) ^ ((r & 7) << 4));
      *(ushort*)((char*)At + byte) = f2bf(v);
    }
  }
  __syncthreads();
  const int w = t >> 6, l = t & 63, lr = l & 15, lg = l >> 4;
  f32x4 acc[4][4] = {};
  for (int kb = 0; kb < 5; kb++){
    s16x8 a[4], b[4];
    #pragma unroll
    for (int m = 0; m < 4; m++){
      int row = m * 16 + lr;
      int cb = (kb * 64 + (lg << 4)) ^ ((row & 7) << 4);
      a[m] = *(const s16x8*)((const char*)At + row * 384 + cb);
    }
    #pragma unroll
    for (int n = 0; n < 4; n++){
      int fi = (w * 4 + n) * 5 + kb;
      b[n] = *(const s16x8*)(Bf + (size_t)(fi * 64 + l) * 8);
    }
    #pragma unroll
    for (int m = 0; m < 4; m++)
      #pragma unroll
      for (int n = 0; n < 4; n++)
        acc[m][n] = mfma16(a[m], b[n], acc[m][n]);
  }
  #pragma unroll
  for (int m = 0; m < 4; m++){
    #pragma unroll
    for (int n = 0; n < 4; n++){
      long base = (r0 + m * 16 + lg * 4) * 256 + (w * 64 + n * 16 + lr);
      #pragma unroll
      for (int r = 0; r < 4; r++){
        float v = acc[m][n][r];
        long ad = base + (long)r * 256;
        if (out_pre)  out_pre[ad]  = f2bf(v);
        if (out_relu) out_relu[ad] = f2bf(v > 0.f ? v : 0.f);
      }
    }
  }
}

// ---------------- message-passing GEMM ----------------
// msg_out = relu(inp + (amsg[src[e]] - msg_in[e^1]) @ W_h)
__global__ __launch_bounds__(256) void k_mp(
    const ushort* __restrict__ inp16, const ushort* __restrict__ amsg,
    const ushort* __restrict__ msg_in, const ushort* __restrict__ Whf,
    const int* __restrict__ srcidx, ushort* __restrict__ msg_out){
  __shared__ ushort At[64 * 256]; // pitch 512B, XOR-swizzled
  const int t = threadIdx.x;
  const long e0 = (long)blockIdx.x * 64;
  {
    const int r = t >> 2, q = t & 3;
    const long e = e0 + r;
    const int s = srcidx[e];
    const long re = e ^ 1;
    const ushort* pa = amsg   + (size_t)s * 256 + q * 64;
    const ushort* pm = msg_in + re * 256 + q * 64;
    #pragma unroll
    for (int i = 0; i < 8; i++){
      s16x8 va = *(const s16x8*)(pa + i * 8);
      s16x8 vm = *(const s16x8*)(pm + i * 8);
      s16x8 res;
      #pragma unroll
      for (int j = 0; j < 8; j++)
        res[j] = (short)f2bf(bf2f((unsigned short)va[j]) - bf2f((unsigned short)vm[j]));
      int byte = r * 512 + ((q * 128 + i * 16) ^ ((r & 7) << 4));
      *(s16x8*)((char*)At + byte) = res;
    }
  }
  __syncthreads();
  const int w = t >> 6, l = t & 63, lr = l & 15, lg = l >> 4;
  f32x4 acc[4][4] = {};
  for (int kb = 0; kb < 8; kb++){
    s16x8 a[4], b[4];
    #pragma unroll
    for (int m = 0; m < 4; m++){
      int row = m * 16 + lr;
      int cb = (kb * 64 + (lg << 4)) ^ ((row & 7) << 4);
      a[m] = *(const s16x8*)((const char*)At + row * 512 + cb);
    }
    #pragma unroll
    for (int n = 0; n < 4; n++){
      int fi = (w * 4 + n) * 8 + kb;
      b[n] = *(const s16x8*)(Whf + (size_t)(fi * 64 + l) * 8);
    }
    #pragma unroll
    for (int m = 0; m < 4; m++)
      #pragma unroll
      for (int n = 0; n < 4; n++)
        acc[m][n] = mfma16(a[m], b[n], acc[m][n]);
  }
  #pragma unroll
  for (int m = 0; m < 4; m++){
    #pragma unroll
    for (int n = 0; n < 4; n++){
      long base = (e0 + m * 16 + lg * 4) * 256 + (w * 64 + n * 16 + lr);
      #pragma unroll
      for (int r = 0; r < 4; r++){
        long ad = base + (long)r * 256;
        float v = acc[m][n][r] + bf2f(inp16[ad]);
        msg_out[ad] = f2bf(v > 0.f ? v : 0.f);
      }
    }
  }
}

// ---------------- segment sum: one wave per atom ----------------
__global__ __launch_bounds__(256) void k_segsum(
    const ushort* __restrict__ msg, const int* __restrict__ offs,
    const int* __restrict__ elist, ushort* __restrict__ amsg){
  const int t = threadIdx.x, w = t >> 6, l = t & 63;
  const int a = blockIdx.x * 4 + w;
  const int beg = offs[a], end = offs[a + 1];
  float a0 = 0, a1 = 0, a2 = 0, a3 = 0;
  for (int i = beg; i < end; i++){
    int e = elist[i];
    const ushort4 v = *(const ushort4*)(msg + (size_t)e * 256 + l * 4);
    a0 += bf2f(v.x); a1 += bf2f(v.y); a2 += bf2f(v.z); a3 += bf2f(v.w);
  }
  ushort4 o; o.x = f2bf(a0); o.y = f2bf(a1); o.z = f2bf(a2); o.w = f2bf(a3);
  *(ushort4*)(amsg + (size_t)a * 256 + l * 4) = o;
}

// ---------------- W_o part B: ah = relu(amsg @ Wo2 + partial + b_o) ----------------
__global__ __launch_bounds__(256) void k_woB(
    const ushort* __restrict__ amsg, const ushort* __restrict__ Wof2,
    const ushort* __restrict__ partial, const float* __restrict__ b_o,
    ushort* __restrict__ ah){
  const int t = threadIdx.x, w = t >> 6, l = t & 63, lr = l & 15, lg = l >> 4;
  const long r0 = (long)blockIdx.x * 64;
  f32x4 acc[4][4] = {};
  for (int kb = 0; kb < 8; kb++){
    s16x8 a[4], b[4];
    #pragma unroll
    for (int m = 0; m < 4; m++)
      a[m] = *(const s16x8*)(amsg + (r0 + m * 16 + lr) * 256 + kb * 32 + lg * 8);
    #pragma unroll
    for (int n = 0; n < 4; n++)
      b[n] = *(const s16x8*)(Wof2 + (size_t)(((w * 4 + n) * 8 + kb) * 64 + l) * 8);
    #pragma unroll
    for (int m = 0; m < 4; m++)
      #pragma unroll
      for (int n = 0; n < 4; n++)
        acc[m][n] = mfma16(a[m], b[n], acc[m][n]);
  }
  #pragma unroll
  for (int m = 0; m < 4; m++){
    #pragma unroll
    for (int n = 0; n < 4; n++){
      int col = w * 64 + n * 16 + lr;
      float bo = b_o[col];
      long base = (r0 + m * 16 + lg * 4) * 256 + col;
      #pragma unroll
      for (int r = 0; r < 4; r++){
        long ad = base + (long)r * 256;
        float v = acc[m][n][r] + bf2f(partial[ad]) + bo;
        ah[ad] = f2bf(v > 0.f ? v : 0.f);
      }
    }
  }
}

// ---------------- node head: out = ah @ node_W + node_b (fp32 out, 133 cols) ----------------
__global__ __launch_bounds__(192) void k_node(
    const ushort* __restrict__ ah, const ushort* __restrict__ nWf,
    const float* __restrict__ node_b, float* __restrict__ out_node){
  const int t = threadIdx.x, w = t >> 6, l = t & 63, lr = l & 15, lg = l >> 4;
  const long r0 = (long)blockIdx.x * 64;
  f32x4 acc[4][3] = {};
  for (int kb = 0; kb < 8; kb++){
    s16x8 a[4], b[3];
    #pragma unroll
    for (int m = 0; m < 4; m++)
      a[m] = *(const s16x8*)(ah + (r0 + m * 16 + lr) * 256 + kb * 32 + lg * 8);
    #pragma unroll
    for (int n = 0; n < 3; n++)
      b[n] = *(const s16x8*)(nWf + (size_t)(((w * 3 + n) * 8 + kb) * 64 + l) * 8);
    #pragma unroll
    for (int m = 0; m < 4; m++)
      #pragma unroll
      for (int n = 0; n < 3; n++)
        acc[m][n] = mfma16(a[m], b[n], acc[m][n]);
  }
  #pragma unroll
  for (int m = 0; m < 4; m++){
    #pragma unroll
    for (int n = 0; n < 3; n++){
      int col = (w * 3 + n) * 16 + lr;
      if (col < AF){
        float nb = node_b[col];
        #pragma unroll
        for (int r = 0; r < 4; r++)
          out_node[(r0 + m * 16 + lg * 4 + r) * AF + col] = acc[m][n][r] + nb;
      }
    }
  }
}

// ---------------- edge projection: proj = ah @ edge_W (f32, 16 cols padded) ----------------
__global__ __launch_bounds__(64) void k_proj(
    const ushort* __restrict__ ah, const ushort* __restrict__ eWf,
    float* __restrict__ proj){
  const int l = threadIdx.x, lr = l & 15, lg = l >> 4;
  const long r0 = (long)blockIdx.x * 64;
  f32x4 acc[4] = {};
  for (int kb = 0; kb < 8; kb++){
    s16x8 b = *(const s16x8*)(eWf + (size_t)(kb * 64 + l) * 8);
    #pragma unroll
    for (int m = 0; m < 4; m++){
      s16x8 a = *(const s16x8*)(ah + (r0 + m * 16 + lr) * 256 + kb * 32 + lg * 8);
      acc[m] = mfma16(a, b, acc[m]);
    }
  }
  #pragma unroll
  for (int m = 0; m < 4; m++)
    #pragma unroll
    for (int r = 0; r < 4; r++)
      proj[(r0 + m * 16 + lg * 4 + r) * 16 + lr] = acc[m][r];
}

__global__ void k_edge_out(const int* __restrict__ edge_index, const float* __restrict__ proj,
                           const float* __restrict__ edge_b, float* __restrict__ out_edge){
  int gid = blockIdx.x * 256 + threadIdx.x;
  int i = gid >> 4, c = gid & 15;
  if (c < BFdim){
    int s = edge_index[2 * i];
    int d = edge_index[NEDGES + 2 * i];
    out_edge[(size_t)i * BFdim + c] =
        0.5f * (proj[(size_t)s * 16 + c] + proj[(size_t)d * 16 + c]) + edge_b[c];
  }
}

// ---------------- molecule pooling ----------------
__global__ __launch_bounds__(256) void k_pool(const ushort* __restrict__ ah,
                                              const int* __restrict__ molst,
                                              float* __restrict__ gemb){
  const int t = threadIdx.x, w = t >> 6, l = t & 63;
  const int m = blockIdx.x * 4 + w;
  const int beg = molst[m], end = molst[m + 1];
  float a0 = 0, a1 = 0, a2 = 0, a3 = 0;
  for (int i = beg; i < end; i++){
    const ushort4 v = *(const ushort4*)(ah + (size_t)i * 256 + l * 4);
    a0 += bf2f(v.x); a1 += bf2f(v.y); a2 += bf2f(v.z); a3 += bf2f(v.w);
  }
  f32x4 o = {a0, a1, a2, a3};
  *(f32x4*)(gemb + (size_t)m * 256 + l * 4) = o;
}

// ---------------- graph head (fp32) ----------------
__global__ __launch_bounds__(256) void k_g1(const float* __restrict__ gemb,
                                            const float* __restrict__ gW1,
                                            const float* __restrict__ gb1,
                                            float* __restrict__ ghid){
  __shared__ float s[16 * 256];
  const int t = threadIdx.x;
  const int r0 = blockIdx.x * 16;
  for (int i = 0; i < 16; i++){
    int r = r0 + i;
    s[i * 256 + t] = (r < NMOLS) ? gemb[(size_t)r * 256 + t] : 0.f;
  }
  __syncthreads();
  float acc[16] = {};
  for (int k = 0; k < 256; k++){
    float wv = gW1[(size_t)k * 256 + t];
    #pragma unroll
    for (int i = 0; i < 16; i++) acc[i] += s[i * 256 + k] * wv;
  }
  float b = gb1[t];
  for (int i = 0; i < 16; i++){
    int r = r0 + i;
    if (r < NMOLS){ float v = acc[i] + b; ghid[(size_t)r * 256 + t] = v > 0.f ? v : 0.f; }
  }
}
__global__ void k_g2(const float* __restrict__ ghid, const float* __restrict__ gW2,
                     const float* __restrict__ gb2, float* __restrict__ outg){
  const int t = threadIdx.x, w = t >> 6, l = t & 63;
  const int m = blockIdx.x * 4 + w;
  f32x4 v = *(const f32x4*)(ghid + (size_t)m * 256 + l * 4);
  const f32x4 wv = *(const f32x4*)(gW2 + l * 4);
  float acc = v[0] * wv[0] + v[1] * wv[1] + v[2] * wv[2] + v[3] * wv[3];
  for (int ofs = 32; ofs; ofs >>= 1) acc += __shfl_down(acc, ofs, 64);
  if (l == 0) outg[m] = acc + gb2[0];
}

extern "C" void kernel_launch(void* const* d_in, const int* in_sizes, int n_in,
                              void* d_out, int out_size, void* d_ws, size_t ws_size,
                              hipStream_t stream){
  const float* f_atoms = (const float*)d_in[0];
  const float* f_bonds = (const float*)d_in[1];
  const float* W_i     = (const float*)d_in[2];
  const float* W_h     = (const float*)d_in[3];
  const float* W_o     = (const float*)d_in[4];
  const float* b_o     = (const float*)d_in[5];
  const float* node_W  = (const float*)d_in[6];
  const float* node_b  = (const float*)d_in[7];
  const float* edge_W  = (const float*)d_in[8];
  const float* edge_b  = (const float*)d_in[9];
  const float* g_W1    = (const float*)d_in[10];
  const float* g_b1    = (const float*)d_in[11];
  const float* g_W2    = (const float*)d_in[12];
  const float* g_b2    = (const float*)d_in[13];
  const int* edge_index = (const int*)d_in[14];
  const int* atom_mol   = (const int*)d_in[16];

  float* out_node  = (float*)d_out;
  float* out_edge  = out_node + (size_t)NATOMS * AF;
  float* out_graph = out_edge + (size_t)(NEDGES / 2) * BFdim;

  char* p = (char*)d_ws;
  auto alloc = [&](size_t b) -> char* { char* r = p; p += (b + 255) & ~(size_t)255; return r; };
  ushort* inp16 = (ushort*)alloc((size_t)NEDGES * 256 * 2);
  ushort* msgA  = (ushort*)alloc((size_t)NEDGES * 256 * 2);
  ushort* msgB  = (ushort*)alloc((size_t)NEDGES * 256 * 2);
  ushort* amsg  = (ushort*)alloc((size_t)NATOMS * 256 * 2);
  ushort* ah    = (ushort*)alloc((size_t)NATOMS * 256 * 2);
  float*  proj  = (float*)alloc((size_t)NATOMS * 16 * 4);
  float*  gemb  = (float*)alloc((size_t)NMOLS * 256 * 4);
  float*  ghid  = (float*)alloc((size_t)NMOLS * 256 * 4);
  ushort* Wif   = (ushort*)alloc(160 * 256 * 2);
  ushort* Wof1  = (ushort*)alloc(160 * 256 * 2);
  ushort* Whf   = (ushort*)alloc(256 * 256 * 2);
  ushort* Wof2  = (ushort*)alloc(256 * 256 * 2);
  ushort* nWf   = (ushort*)alloc(256 * 144 * 2);
  ushort* eWf   = (ushort*)alloc(256 * 16 * 2);
  int* deg    = (int*)alloc(NATOMS * 4);
  int* offs   = (int*)alloc((NATOMS + 1) * 4);
  int* cursor = (int*)alloc(NATOMS * 4);
  int* elist  = (int*)alloc(NEDGES * 4);
  int* bsum   = (int*)alloc(1568 * 4);
  int* boff   = (int*)alloc(1568 * 4);
  int* molst  = (int*)alloc((NMOLS + 1) * 4);
  if ((size_t)(p - (char*)d_ws) > ws_size) return;

  const int* dsti = edge_index + NEDGES;

  hipMemsetAsync(deg, 0, NATOMS * 4, stream);
  k_prep_weights<<<992, 256, 0, stream>>>(W_i, W_h, W_o, node_W, edge_W,
                                          Wif, Wof1, Whf, Wof2, nWf, eWf);
  k_hist<<<3125, 256, 0, stream>>>(dsti, deg);
  k_blocksum<<<NBLK, 256, 0, stream>>>(deg, bsum);
  k_scanblk<<<1, 1024, 0, stream>>>(bsum, boff);
  k_offs<<<NBLK, 256, 0, stream>>>(deg, boff, offs, cursor);
  k_fill<<<3125, 256, 0, stream>>>(dsti, cursor, elist);
  k_molstart<<<51, 256, 0, stream>>>(atom_mol, molst);

  // inp = f_bonds @ W_i ; msgA = relu(inp)
  k_skinny<<<12500, 256, 0, stream>>>(f_bonds, BFD, Wif, inp16, msgA);
  // depth iterations
  k_segsum<<<100000, 256, 0, stream>>>(msgA, offs, elist, amsg);
  k_mp<<<12500, 256, 0, stream>>>(inp16, amsg, msgA, Whf, edge_index, msgB);
  k_segsum<<<100000, 256, 0, stream>>>(msgB, offs, elist, amsg);
  k_mp<<<12500, 256, 0, stream>>>(inp16, amsg, msgB, Whf, edge_index, msgA);
  k_segsum<<<100000, 256, 0, stream>>>(msgA, offs, elist, amsg);
  // atom_hiddens = relu(f_atoms @ Wo1 + amsg @ Wo2 + b_o)   (partial in msgB)
  k_skinny<<<6250, 256, 0, stream>>>(f_atoms, AF, Wof1, msgB, (ushort*)nullptr);
  k_woB<<<6250, 256, 0, stream>>>(amsg, Wof2, msgB, b_o, ah);
  // heads
  k_pool<<<3250, 256, 0, stream>>>(ah, molst, gemb);
  k_node<<<6250, 192, 0, stream>>>(ah, nWf, node_b, out_node);
  k_proj<<<6250, 64, 0, stream>>>(ah, eWf, proj);
  k_edge_out<<<25000, 256, 0, stream>>>(edge_index, proj, edge_b, out_edge);
  k_g1<<<813, 256, 0, stream>>>(gemb, g_W1, g_b1, ghid);
  k_g2<<<3250, 256, 0, stream>>>(ghid, g_W2, g_b2, out_graph);
}

// Round 2
// 2978.897 us; speedup vs baseline: 1.2346x; 1.2346x over previous
//
#include <hip/hip_runtime.h>

#define NATOMS 400000
#define NEDGES 800000
#define NMOLS  13000
#define AF 133
#define BFdim 14
#define BFD 147

typedef __attribute__((ext_vector_type(8))) short  s16x8;
typedef __attribute__((ext_vector_type(8))) __bf16 b16x8;
typedef __attribute__((ext_vector_type(4))) float  f32x4;

__device__ __forceinline__ float bf2f(unsigned short u){
  union { unsigned int i; float f; } v; v.i = ((unsigned int)u) << 16; return v.f;
}
__device__ __forceinline__ unsigned short f2bf(float f){
  union { float ff; unsigned int i; } v; v.ff = f;
  unsigned int b = v.i + 0x7fffu + ((v.i >> 16) & 1u);
  return (unsigned short)(b >> 16);
}
__device__ __forceinline__ f32x4 mfma16(s16x8 a, s16x8 b, f32x4 c){
  return __builtin_amdgcn_mfma_f32_16x16x32_bf16(
      __builtin_bit_cast(b16x8, a), __builtin_bit_cast(b16x8, b), c, 0, 0, 0);
}
__device__ __forceinline__ void gload_lds16(const void* g, void* lds){
  __builtin_amdgcn_global_load_lds(
      (const __attribute__((address_space(1))) void*)g,
      (__attribute__((address_space(3))) void*)lds, 16, 0, 0);
}

// ---------------- weight prep: fp32 -> bf16 fragment order ----------------
__global__ void k_prep_weights(const float* __restrict__ W_i, const float* __restrict__ W_h,
                               const float* __restrict__ W_o, const float* __restrict__ node_W,
                               const float* __restrict__ edge_W,
                               ushort* __restrict__ Wif, ushort* __restrict__ Wof1,
                               ushort* __restrict__ Whf, ushort* __restrict__ Wof2,
                               ushort* __restrict__ nWf, ushort* __restrict__ eWf){
  int gid = blockIdx.x * 256 + threadIdx.x;
  ushort* dst; const float* src; int KB, Kv, Ns, idx;
  if      (gid <  40960){ idx = gid;          dst = Wif;  src = W_i;          KB = 5; Kv = 147; Ns = 256; }
  else if (gid <  81920){ idx = gid -  40960; dst = Wof1; src = W_o;          KB = 5; Kv = 133; Ns = 256; }
  else if (gid < 147456){ idx = gid -  81920; dst = Whf;  src = W_h;          KB = 8; Kv = 256; Ns = 256; }
  else if (gid < 212992){ idx = gid - 147456; dst = Wof2; src = W_o + 133*256;KB = 8; Kv = 256; Ns = 256; }
  else if (gid < 249856){ idx = gid - 212992; dst = nWf;  src = node_W;       KB = 8; Kv = 256; Ns = 133; }
  else if (gid < 253952){ idx = gid - 249856; dst = eWf;  src = edge_W;       KB = 8; Kv = 256; Ns = 14;  }
  else return;
  int j = idx & 7, lane = (idx >> 3) & 63, fi = idx >> 9;
  int kb = fi % KB, nb = fi / KB;
  int k = kb * 32 + ((lane >> 4) << 3) + j;
  int n = nb * 16 + (lane & 15);
  float v = 0.f;
  if (k < Kv && n < Ns) v = src[(size_t)k * Ns + n];
  dst[idx] = f2bf(v);
}

// ---------------- CSR build over dst ----------------
__global__ void k_hist(const int* __restrict__ dsti, int* __restrict__ deg){
  int e = blockIdx.x * 256 + threadIdx.x;
  if (e < NEDGES) atomicAdd(&deg[dsti[e]], 1);
}
__global__ void k_blocksum(const int* __restrict__ deg, int* __restrict__ bsum){
  __shared__ int s[256];
  int i = blockIdx.x * 256 + threadIdx.x;
  s[threadIdx.x] = (i < NATOMS) ? deg[i] : 0;
  __syncthreads();
  for (int st = 128; st > 0; st >>= 1){
    if (threadIdx.x < st) s[threadIdx.x] += s[threadIdx.x + st];
    __syncthreads();
  }
  if (threadIdx.x == 0) bsum[blockIdx.x] = s[0];
}
#define NBLK 1563
__global__ void k_scanblk(const int* __restrict__ bs, int* __restrict__ bo){
  __shared__ int s[2048];
  int t = threadIdx.x;
  s[2*t]   = (2*t   < NBLK) ? bs[2*t]   : 0;
  s[2*t+1] = (2*t+1 < NBLK) ? bs[2*t+1] : 0;
  int offset = 1;
  for (int d = 1024; d > 0; d >>= 1){
    __syncthreads();
    if (t < d){ int ai = offset*(2*t+1)-1, bi = offset*(2*t+2)-1; s[bi] += s[ai]; }
    offset <<= 1;
  }
  __syncthreads();
  if (t == 0) s[2047] = 0;
  for (int d = 1; d < 2048; d <<= 1){
    offset >>= 1;
    __syncthreads();
    if (t < d){ int ai = offset*(2*t+1)-1, bi = offset*(2*t+2)-1;
                int tmp = s[ai]; s[ai] = s[bi]; s[bi] += tmp; }
  }
  __syncthreads();
  if (2*t   < NBLK) bo[2*t]   = s[2*t];
  if (2*t+1 < NBLK) bo[2*t+1] = s[2*t+1];
}
__global__ void k_offs(const int* __restrict__ deg, const int* __restrict__ bo,
                       int* __restrict__ offs, int* __restrict__ cursor){
  __shared__ int s1[256], s2[256];
  int t = threadIdx.x;
  int i = blockIdx.x * 256 + t;
  int v = (i < NATOMS) ? deg[i] : 0;
  s1[t] = v;
  __syncthreads();
  int* rd = s1; int* wr = s2;
  for (int ofs = 1; ofs < 256; ofs <<= 1){
    wr[t] = rd[t] + ((t >= ofs) ? rd[t - ofs] : 0);
    __syncthreads();
    int* tmp = rd; rd = wr; wr = tmp;
  }
  if (i < NATOMS){
    int excl = rd[t] - v + bo[blockIdx.x];
    offs[i] = excl; cursor[i] = excl;
  }
  if (i == 0) offs[NATOMS] = NEDGES;
}
__global__ void k_fill(const int* __restrict__ dsti, int* __restrict__ cursor,
                       int* __restrict__ elist){
  int e = blockIdx.x * 256 + threadIdx.x;
  if (e < NEDGES){ int pos = atomicAdd(&cursor[dsti[e]], 1); elist[pos] = e; }
}
__global__ void k_molstart(const int* __restrict__ atom_mol, int* __restrict__ molst){
  int m = blockIdx.x * 256 + threadIdx.x;
  if (m > NMOLS) return;
  int lo = 0, hi = NATOMS;
  while (lo < hi){ int mid = (lo + hi) >> 1; if (atom_mol[mid] < m) lo = mid + 1; else hi = mid; }
  molst[m] = lo;
}

// ---------------- skinny-K GEMM (fp32 A rows): out_pre / out_relu ----------------
__global__ __launch_bounds__(256) void k_skinny(
    const float* __restrict__ A, int rowlen,
    const ushort* __restrict__ Bf,
    ushort* __restrict__ out_pre, ushort* __restrict__ out_relu){
  __shared__ ushort At[64 * 192]; // pitch 384B, XOR-swizzled
  const int t = threadIdx.x;
  const long r0 = (long)blockIdx.x * 64;
  {
    const int r = t >> 2, q = t & 3;
    const float* ap = A + (r0 + r) * rowlen;
    #pragma unroll 8
    for (int jj = 0; jj < 40; jj++){
      int c = q + (jj << 2);
      float v = (c < rowlen) ? ap[c] : 0.f;
      int byte = r * 384 + ((c * 2) ^ ((r & 7) << 4));
      *(ushort*)((char*)At + byte) = f2bf(v);
    }
  }
  __syncthreads();
  const int w = t >> 6, l = t & 63, lr = l & 15, lg = l >> 4;
  f32x4 acc[4][4] = {};
  for (int kb = 0; kb < 5; kb++){
    s16x8 a[4], b[4];
    #pragma unroll
    for (int m = 0; m < 4; m++){
      int row = m * 16 + lr;
      int cb = (kb * 64 + (lg << 4)) ^ ((row & 7) << 4);
      a[m] = *(const s16x8*)((const char*)At + row * 384 + cb);
    }
    #pragma unroll
    for (int n = 0; n < 4; n++){
      int fi = (w * 4 + n) * 5 + kb;
      b[n] = *(const s16x8*)(Bf + (size_t)(fi * 64 + l) * 8);
    }
    #pragma unroll
    for (int m = 0; m < 4; m++)
      #pragma unroll
      for (int n = 0; n < 4; n++)
        acc[m][n] = mfma16(a[m], b[n], acc[m][n]);
  }
  #pragma unroll
  for (int m = 0; m < 4; m++){
    #pragma unroll
    for (int n = 0; n < 4; n++){
      long base = (r0 + m * 16 + lg * 4) * 256 + (w * 64 + n * 16 + lr);
      #pragma unroll
      for (int r = 0; r < 4; r++){
        float v = acc[m][n][r];
        long ad = base + (long)r * 256;
        if (out_pre)  out_pre[ad]  = f2bf(v);
        if (out_relu) out_relu[ad] = f2bf(v > 0.f ? v : 0.f);
      }
    }
  }
}

// ---------------- dense E-row GEMM: Y = A @ Whf  (bf16 out, no epilogue) ----------------
// 64 rows/block, N=256, K=256 fully LDS-resident, global_load_lds + XOR swizzle.
__global__ __launch_bounds__(256) void k_Y(
    const ushort* __restrict__ A, const ushort* __restrict__ Whf,
    ushort* __restrict__ Yout){
  __shared__ ushort At[64 * 256]; // 32KB: [row][512B], byte col c stored at c^((row&7)<<4)
  const int t = threadIdx.x, w = t >> 6, l = t & 63;
  const long e0 = (long)blockIdx.x * 64;
  const char* Ab = (const char*)(A + e0 * 256);
  #pragma unroll
  for (int i = 0; i < 8; i++){
    int dbase = w * 8192 + i * 1024;        // wave-uniform LDS byte base
    int d = dbase + l * 16;                 // this lane's linear LDS byte
    int sw = ((d >> 9) & 7) << 4;           // row = d>>9
    gload_lds16(Ab + (d ^ sw), (char*)At + dbase);
  }
  __syncthreads();
  const int lr = l & 15, lg = l >> 4;
  f32x4 acc[4][4] = {};
  for (int kb = 0; kb < 8; kb++){
    s16x8 a[4], b[4];
    #pragma unroll
    for (int m = 0; m < 4; m++){
      int row = m * 16 + lr;
      int cb = (kb * 64 + (lg << 4)) ^ ((row & 7) << 4);
      a[m] = *(const s16x8*)((const char*)At + row * 512 + cb);
    }
    #pragma unroll
    for (int n = 0; n < 4; n++){
      int fi = (w * 4 + n) * 8 + kb;
      b[n] = *(const s16x8*)(Whf + (size_t)(fi * 64 + l) * 8);
    }
    #pragma unroll
    for (int m = 0; m < 4; m++)
      #pragma unroll
      for (int n = 0; n < 4; n++)
        acc[m][n] = mfma16(a[m], b[n], acc[m][n]);
  }
  #pragma unroll
  for (int m = 0; m < 4; m++){
    #pragma unroll
    for (int n = 0; n < 4; n++){
      long base = (e0 + m * 16 + lg * 4) * 256 + (w * 64 + n * 16 + lr);
      #pragma unroll
      for (int r = 0; r < 4; r++)
        Yout[base + (long)r * 256] = f2bf(acc[m][n][r]);
    }
  }
}

// ---------------- fused segsum+combine ----------------
// per atom a (one wave): S = sum_{dst[j]=a} Y[j];
// for each such j: msg_out[j^1] = relu(inp[j^1] + S - Y[j])
__global__ __launch_bounds__(256) void k_fused(
    const ushort* __restrict__ Y, const ushort* __restrict__ inp16,
    const int* __restrict__ offs, const int* __restrict__ elist,
    ushort* __restrict__ msg_out){
  const int t = threadIdx.x, w = t >> 6, l = t & 63;
  const int a = blockIdx.x * 4 + w;
  const int beg = offs[a], end = offs[a + 1];
  float s0 = 0, s1 = 0, s2 = 0, s3 = 0;
  for (int i = beg; i < end; i++){
    int e = elist[i];
    const ushort4 v = *(const ushort4*)(Y + (size_t)e * 256 + l * 4);
    s0 += bf2f(v.x); s1 += bf2f(v.y); s2 += bf2f(v.z); s3 += bf2f(v.w);
  }
  for (int i = beg; i < end; i++){
    int e = elist[i];
    const ushort4 vy = *(const ushort4*)(Y + (size_t)e * 256 + l * 4);
    long j1 = (long)(e ^ 1);
    const ushort4 vi = *(const ushort4*)(inp16 + j1 * 256 + l * 4);
    ushort4 o;
    float r0 = bf2f(vi.x) + s0 - bf2f(vy.x); o.x = f2bf(r0 > 0.f ? r0 : 0.f);
    float r1 = bf2f(vi.y) + s1 - bf2f(vy.y); o.y = f2bf(r1 > 0.f ? r1 : 0.f);
    float r2 = bf2f(vi.z) + s2 - bf2f(vy.z); o.z = f2bf(r2 > 0.f ? r2 : 0.f);
    float r3 = bf2f(vi.w) + s3 - bf2f(vy.w); o.w = f2bf(r3 > 0.f ? r3 : 0.f);
    *(ushort4*)(msg_out + j1 * 256 + l * 4) = o;
  }
}

// ---------------- segment sum (final): one wave per atom ----------------
__global__ __launch_bounds__(256) void k_segsum(
    const ushort* __restrict__ msg, const int* __restrict__ offs,
    const int* __restrict__ elist, ushort* __restrict__ amsg){
  const int t = threadIdx.x, w = t >> 6, l = t & 63;
  const int a = blockIdx.x * 4 + w;
  const int beg = offs[a], end = offs[a + 1];
  float a0 = 0, a1 = 0, a2 = 0, a3 = 0;
  for (int i = beg; i < end; i++){
    int e = elist[i];
    const ushort4 v = *(const ushort4*)(msg + (size_t)e * 256 + l * 4);
    a0 += bf2f(v.x); a1 += bf2f(v.y); a2 += bf2f(v.z); a3 += bf2f(v.w);
  }
  ushort4 o; o.x = f2bf(a0); o.y = f2bf(a1); o.z = f2bf(a2); o.w = f2bf(a3);
  *(ushort4*)(amsg + (size_t)a * 256 + l * 4) = o;
}

// ---------------- W_o part B: ah = relu(amsg @ Wo2 + partial + b_o) ----------------
__global__ __launch_bounds__(256) void k_woB(
    const ushort* __restrict__ amsg, const ushort* __restrict__ Wof2,
    const ushort* __restrict__ partial, const float* __restrict__ b_o,
    ushort* __restrict__ ah){
  const int t = threadIdx.x, w = t >> 6, l = t & 63, lr = l & 15, lg = l >> 4;
  const long r0 = (long)blockIdx.x * 64;
  f32x4 acc[4][4] = {};
  for (int kb = 0; kb < 8; kb++){
    s16x8 a[4], b[4];
    #pragma unroll
    for (int m = 0; m < 4; m++)
      a[m] = *(const s16x8*)(amsg + (r0 + m * 16 + lr) * 256 + kb * 32 + lg * 8);
    #pragma unroll
    for (int n = 0; n < 4; n++)
      b[n] = *(const s16x8*)(Wof2 + (size_t)(((w * 4 + n) * 8 + kb) * 64 + l) * 8);
    #pragma unroll
    for (int m = 0; m < 4; m++)
      #pragma unroll
      for (int n = 0; n < 4; n++)
        acc[m][n] = mfma16(a[m], b[n], acc[m][n]);
  }
  #pragma unroll
  for (int m = 0; m < 4; m++){
    #pragma unroll
    for (int n = 0; n < 4; n++){
      int col = w * 64 + n * 16 + lr;
      float bo = b_o[col];
      long base = (r0 + m * 16 + lg * 4) * 256 + col;
      #pragma unroll
      for (int r = 0; r < 4; r++){
        long ad = base + (long)r * 256;
        float v = acc[m][n][r] + bf2f(partial[ad]) + bo;
        ah[ad] = f2bf(v > 0.f ? v : 0.f);
      }
    }
  }
}

// ---------------- node head ----------------
__global__ __launch_bounds__(192) void k_node(
    const ushort* __restrict__ ah, const ushort* __restrict__ nWf,
    const float* __restrict__ node_b, float* __restrict__ out_node){
  const int t = threadIdx.x, w = t >> 6, l = t & 63, lr = l & 15, lg = l >> 4;
  const long r0 = (long)blockIdx.x * 64;
  f32x4 acc[4][3] = {};
  for (int kb = 0; kb < 8; kb++){
    s16x8 a[4], b[3];
    #pragma unroll
    for (int m = 0; m < 4; m++)
      a[m] = *(const s16x8*)(ah + (r0 + m * 16 + lr) * 256 + kb * 32 + lg * 8);
    #pragma unroll
    for (int n = 0; n < 3; n++)
      b[n] = *(const s16x8*)(nWf + (size_t)(((w * 3 + n) * 8 + kb) * 64 + l) * 8);
    #pragma unroll
    for (int m = 0; m < 4; m++)
      #pragma unroll
      for (int n = 0; n < 3; n++)
        acc[m][n] = mfma16(a[m], b[n], acc[m][n]);
  }
  #pragma unroll
  for (int m = 0; m < 4; m++){
    #pragma unroll
    for (int n = 0; n < 3; n++){
      int col = (w * 3 + n) * 16 + lr;
      if (col < AF){
        float nb = node_b[col];
        #pragma unroll
        for (int r = 0; r < 4; r++)
          out_node[(r0 + m * 16 + lg * 4 + r) * AF + col] = acc[m][n][r] + nb;
      }
    }
  }
}

// ---------------- edge projection ----------------
__global__ __launch_bounds__(64) void k_proj(
    const ushort* __restrict__ ah, const ushort* __restrict__ eWf,
    float* __restrict__ proj){
  const int l = threadIdx.x, lr = l & 15, lg = l >> 4;
  const long r0 = (long)blockIdx.x * 64;
  f32x4 acc[4] = {};
  for (int kb = 0; kb < 8; kb++){
    s16x8 b = *(const s16x8*)(eWf + (size_t)(kb * 64 + l) * 8);
    #pragma unroll
    for (int m = 0; m < 4; m++){
      s16x8 a = *(const s16x8*)(ah + (r0 + m * 16 + lr) * 256 + kb * 32 + lg * 8);
      acc[m] = mfma16(a, b, acc[m]);
    }
  }
  #pragma unroll
  for (int m = 0; m < 4; m++)
    #pragma unroll
    for (int r = 0; r < 4; r++)
      proj[(r0 + m * 16 + lg * 4 + r) * 16 + lr] = acc[m][r];
}

__global__ void k_edge_out(const int* __restrict__ edge_index, const float* __restrict__ proj,
                           const float* __restrict__ edge_b, float* __restrict__ out_edge){
  int gid = blockIdx.x * 256 + threadIdx.x;
  int i = gid >> 4, c = gid & 15;
  if (c < BFdim){
    int s = edge_index[2 * i];
    int d = edge_index[NEDGES + 2 * i];
    out_edge[(size_t)i * BFdim + c] =
        0.5f * (proj[(size_t)s * 16 + c] + proj[(size_t)d * 16 + c]) + edge_b[c];
  }
}

// ---------------- molecule pooling ----------------
__global__ __launch_bounds__(256) void k_pool(const ushort* __restrict__ ah,
                                              const int* __restrict__ molst,
                                              float* __restrict__ gemb){
  const int t = threadIdx.x, w = t >> 6, l = t & 63;
  const int m = blockIdx.x * 4 + w;
  const int beg = molst[m], end = molst[m + 1];
  float a0 = 0, a1 = 0, a2 = 0, a3 = 0;
  for (int i = beg; i < end; i++){
    const ushort4 v = *(const ushort4*)(ah + (size_t)i * 256 + l * 4);
    a0 += bf2f(v.x); a1 += bf2f(v.y); a2 += bf2f(v.z); a3 += bf2f(v.w);
  }
  f32x4 o = {a0, a1, a2, a3};
  *(f32x4*)(gemb + (size_t)m * 256 + l * 4) = o;
}

// ---------------- graph head (fp32) ----------------
__global__ __launch_bounds__(256) void k_g1(const float* __restrict__ gemb,
                                            const float* __restrict__ gW1,
                                            const float* __restrict__ gb1,
                                            float* __restrict__ ghid){
  __shared__ float s[16 * 256];
  const int t = threadIdx.x;
  const int r0 = blockIdx.x * 16;
  for (int i = 0; i < 16; i++){
    int r = r0 + i;
    s[i * 256 + t] = (r < NMOLS) ? gemb[(size_t)r * 256 + t] : 0.f;
  }
  __syncthreads();
  float acc[16] = {};
  for (int k = 0; k < 256; k++){
    float wv = gW1[(size_t)k * 256 + t];
    #pragma unroll
    for (int i = 0; i < 16; i++) acc[i] += s[i * 256 + k] * wv;
  }
  float b = gb1[t];
  for (int i = 0; i < 16; i++){
    int r = r0 + i;
    if (r < NMOLS){ float v = acc[i] + b; ghid[(size_t)r * 256 + t] = v > 0.f ? v : 0.f; }
  }
}
__global__ void k_g2(const float* __restrict__ ghid, const float* __restrict__ gW2,
                     const float* __restrict__ gb2, float* __restrict__ outg){
  const int t = threadIdx.x, w = t >> 6, l = t & 63;
  const int m = blockIdx.x * 4 + w;
  f32x4 v = *(const f32x4*)(ghid + (size_t)m * 256 + l * 4);
  const f32x4 wv = *(const f32x4*)(gW2 + l * 4);
  float acc = v[0] * wv[0] + v[1] * wv[1] + v[2] * wv[2] + v[3] * wv[3];
  for (int ofs = 32; ofs; ofs >>= 1) acc += __shfl_down(acc, ofs, 64);
  if (l == 0) outg[m] = acc + gb2[0];
}

extern "C" void kernel_launch(void* const* d_in, const int* in_sizes, int n_in,
                              void* d_out, int out_size, void* d_ws, size_t ws_size,
                              hipStream_t stream){
  const float* f_atoms = (const float*)d_in[0];
  const float* f_bonds = (const float*)d_in[1];
  const float* W_i     = (const float*)d_in[2];
  const float* W_h     = (const float*)d_in[3];
  const float* W_o     = (const float*)d_in[4];
  const float* b_o     = (const float*)d_in[5];
  const float* node_W  = (const float*)d_in[6];
  const float* node_b  = (const float*)d_in[7];
  const float* edge_W  = (const float*)d_in[8];
  const float* edge_b  = (const float*)d_in[9];
  const float* g_W1    = (const float*)d_in[10];
  const float* g_b1    = (const float*)d_in[11];
  const float* g_W2    = (const float*)d_in[12];
  const float* g_b2    = (const float*)d_in[13];
  const int* edge_index = (const int*)d_in[14];
  const int* atom_mol   = (const int*)d_in[16];

  float* out_node  = (float*)d_out;
  float* out_edge  = out_node + (size_t)NATOMS * AF;
  float* out_graph = out_edge + (size_t)(NEDGES / 2) * BFdim;

  char* p = (char*)d_ws;
  auto alloc = [&](size_t b) -> char* { char* r = p; p += (b + 255) & ~(size_t)255; return r; };
  ushort* B1 = (ushort*)alloc((size_t)NEDGES * 256 * 2);  // inp16
  ushort* B2 = (ushort*)alloc((size_t)NEDGES * 256 * 2);  // msg0 / msg1 / msg2
  ushort* B3 = (ushort*)alloc((size_t)NEDGES * 256 * 2);  // Y0 / Y1 / partial
  ushort* amsg  = (ushort*)alloc((size_t)NATOMS * 256 * 2);
  ushort* ah    = (ushort*)alloc((size_t)NATOMS * 256 * 2);
  float*  proj  = (float*)alloc((size_t)NATOMS * 16 * 4);
  float*  gemb  = (float*)alloc((size_t)NMOLS * 256 * 4);
  float*  ghid  = (float*)alloc((size_t)NMOLS * 256 * 4);
  ushort* Wif   = (ushort*)alloc(160 * 256 * 2);
  ushort* Wof1  = (ushort*)alloc(160 * 256 * 2);
  ushort* Whf   = (ushort*)alloc(256 * 256 * 2);
  ushort* Wof2  = (ushort*)alloc(256 * 256 * 2);
  ushort* nWf   = (ushort*)alloc(256 * 144 * 2);
  ushort* eWf   = (ushort*)alloc(256 * 16 * 2);
  int* deg    = (int*)alloc(NATOMS * 4);
  int* offs   = (int*)alloc((NATOMS + 1) * 4);
  int* cursor = (int*)alloc(NATOMS * 4);
  int* elist  = (int*)alloc(NEDGES * 4);
  int* bsum   = (int*)alloc(1568 * 4);
  int* boff   = (int*)alloc(1568 * 4);
  int* molst  = (int*)alloc((NMOLS + 1) * 4);
  if ((size_t)(p - (char*)d_ws) > ws_size) return;

  const int* dsti = edge_index + NEDGES;

  hipMemsetAsync(deg, 0, NATOMS * 4, stream);
  k_prep_weights<<<992, 256, 0, stream>>>(W_i, W_h, W_o, node_W, edge_W,
                                          Wif, Wof1, Whf, Wof2, nWf, eWf);
  k_hist<<<3125, 256, 0, stream>>>(dsti, deg);
  k_blocksum<<<NBLK, 256, 0, stream>>>(deg, bsum);
  k_scanblk<<<1, 1024, 0, stream>>>(bsum, boff);
  k_offs<<<NBLK, 256, 0, stream>>>(deg, boff, offs, cursor);
  k_fill<<<3125, 256, 0, stream>>>(dsti, cursor, elist);
  k_molstart<<<51, 256, 0, stream>>>(atom_mol, molst);

  // inp = f_bonds @ W_i -> B1 ; msg0 = relu(inp) -> B2
  k_skinny<<<12500, 256, 0, stream>>>(f_bonds, BFD, Wif, B1, B2);
  // iter 1: Y0 = msg0 @ W_h ; msg1 = relu(inp + segsum(Y0)[src] - Y0[rev])
  k_Y<<<12500, 256, 0, stream>>>(B2, Whf, B3);
  k_fused<<<100000, 256, 0, stream>>>(B3, B1, offs, elist, B2);
  // iter 2: Y1 = msg1 @ W_h ; msg2 = relu(inp + segsum(Y1)[src] - Y1[rev])
  k_Y<<<12500, 256, 0, stream>>>(B2, Whf, B3);
  k_fused<<<100000, 256, 0, stream>>>(B3, B1, offs, elist, B2);
  // final aggregation
  k_segsum<<<100000, 256, 0, stream>>>(B2, offs, elist, amsg);
  // atom_hiddens = relu(f_atoms @ Wo1 + amsg @ Wo2 + b_o)   (partial in B3)
  k_skinny<<<6250, 256, 0, stream>>>(f_atoms, AF, Wof1, B3, (ushort*)nullptr);
  k_woB<<<6250, 256, 0, stream>>>(amsg, Wof2, B3, b_o, ah);
  // heads
  k_pool<<<3250, 256, 0, stream>>>(ah, molst, gemb);
  k_node<<<6250, 192, 0, stream>>>(ah, nWf, node_b, out_node);
  k_proj<<<6250, 64, 0, stream>>>(ah, eWf, proj);
  k_edge_out<<<25000, 256, 0, stream>>>(edge_index, proj, edge_b, out_edge);
  k_g1<<<813, 256, 0, stream>>>(gemb, g_W1, g_b1, ghid);
  k_g2<<<3250, 256, 0, stream>>>(ghid, g_W2, g_b2, out_graph);
}

// Round 3
// 2774.059 us; speedup vs baseline: 1.3257x; 1.0738x over previous
//
#include <hip/hip_runtime.h>

#define NATOMS 400000
#define NEDGES 800000
#define NMOLS  13000
#define AF 133
#define BFdim 14
#define BFD 147

typedef __attribute__((ext_vector_type(8))) short  s16x8;
typedef __attribute__((ext_vector_type(8))) __bf16 b16x8;
typedef __attribute__((ext_vector_type(4))) float  f32x4;

__device__ __forceinline__ float bf2f(unsigned short u){
  union { unsigned int i; float f; } v; v.i = ((unsigned int)u) << 16; return v.f;
}
__device__ __forceinline__ unsigned short f2bf(float f){
  union { float ff; unsigned int i; } v; v.ff = f;
  unsigned int b = v.i + 0x7fffu + ((v.i >> 16) & 1u);
  return (unsigned short)(b >> 16);
}
__device__ __forceinline__ f32x4 mfma16(s16x8 a, s16x8 b, f32x4 c){
  return __builtin_amdgcn_mfma_f32_16x16x32_bf16(
      __builtin_bit_cast(b16x8, a), __builtin_bit_cast(b16x8, b), c, 0, 0, 0);
}
__device__ __forceinline__ void gload_lds16(const void* g, void* lds){
  __builtin_amdgcn_global_load_lds(
      (const __attribute__((address_space(1))) void*)g,
      (__attribute__((address_space(3))) void*)lds, 16, 0, 0);
}

// ---------------- fp32 [rows][Kin] -> bf16 [rows][192] (zero-padded) ----------------
__global__ void k_cvt(const float* __restrict__ src, ushort* __restrict__ dst,
                      int total /* rows*48 */, int Kin){
  int gid = blockIdx.x * 256 + threadIdx.x;
  if (gid >= total) return;
  int row = gid / 48;
  int c0 = (gid - row * 48) * 4;
  const float* sp = src + (size_t)row * Kin + c0;
  ushort4 o;
  o.x = (c0     < Kin) ? f2bf(sp[0]) : 0;
  o.y = (c0 + 1 < Kin) ? f2bf(sp[1]) : 0;
  o.z = (c0 + 2 < Kin) ? f2bf(sp[2]) : 0;
  o.w = (c0 + 3 < Kin) ? f2bf(sp[3]) : 0;
  *(ushort4*)(dst + (size_t)row * 192 + c0) = o;
}

// ---------------- weight prep: fp32 -> bf16 fragment order ----------------
__global__ void k_prep_weights(const float* __restrict__ W_i, const float* __restrict__ W_h,
                               const float* __restrict__ W_o, const float* __restrict__ node_W,
                               const float* __restrict__ edge_W,
                               ushort* __restrict__ Wif, ushort* __restrict__ Wof1,
                               ushort* __restrict__ Whf, ushort* __restrict__ Wof2,
                               ushort* __restrict__ nWf, ushort* __restrict__ eWf){
  int gid = blockIdx.x * 256 + threadIdx.x;
  ushort* dst; const float* src; int KB, Kv, Ns, idx;
  if      (gid <  40960){ idx = gid;          dst = Wif;  src = W_i;          KB = 5; Kv = 147; Ns = 256; }
  else if (gid <  81920){ idx = gid -  40960; dst = Wof1; src = W_o;          KB = 5; Kv = 133; Ns = 256; }
  else if (gid < 147456){ idx = gid -  81920; dst = Whf;  src = W_h;          KB = 8; Kv = 256; Ns = 256; }
  else if (gid < 212992){ idx = gid - 147456; dst = Wof2; src = W_o + 133*256;KB = 8; Kv = 256; Ns = 256; }
  else if (gid < 249856){ idx = gid - 212992; dst = nWf;  src = node_W;       KB = 8; Kv = 256; Ns = 133; }
  else if (gid < 253952){ idx = gid - 249856; dst = eWf;  src = edge_W;       KB = 8; Kv = 256; Ns = 14;  }
  else return;
  int j = idx & 7, lane = (idx >> 3) & 63, fi = idx >> 9;
  int kb = fi % KB, nb = fi / KB;
  int k = kb * 32 + ((lane >> 4) << 3) + j;
  int n = nb * 16 + (lane & 15);
  float v = 0.f;
  if (k < Kv && n < Ns) v = src[(size_t)k * Ns + n];
  dst[idx] = f2bf(v);
}

// ---------------- CSR build over dst ----------------
__global__ void k_hist(const int* __restrict__ dsti, int* __restrict__ deg){
  int e = blockIdx.x * 256 + threadIdx.x;
  if (e < NEDGES) atomicAdd(&deg[dsti[e]], 1);
}
__global__ void k_blocksum(const int* __restrict__ deg, int* __restrict__ bsum){
  __shared__ int s[256];
  int i = blockIdx.x * 256 + threadIdx.x;
  s[threadIdx.x] = (i < NATOMS) ? deg[i] : 0;
  __syncthreads();
  for (int st = 128; st > 0; st >>= 1){
    if (threadIdx.x < st) s[threadIdx.x] += s[threadIdx.x + st];
    __syncthreads();
  }
  if (threadIdx.x == 0) bsum[blockIdx.x] = s[0];
}
#define NBLK 1563
__global__ void k_scanblk(const int* __restrict__ bs, int* __restrict__ bo){
  __shared__ int s[2048];
  int t = threadIdx.x;
  s[2*t]   = (2*t   < NBLK) ? bs[2*t]   : 0;
  s[2*t+1] = (2*t+1 < NBLK) ? bs[2*t+1] : 0;
  int offset = 1;
  for (int d = 1024; d > 0; d >>= 1){
    __syncthreads();
    if (t < d){ int ai = offset*(2*t+1)-1, bi = offset*(2*t+2)-1; s[bi] += s[ai]; }
    offset <<= 1;
  }
  __syncthreads();
  if (t == 0) s[2047] = 0;
  for (int d = 1; d < 2048; d <<= 1){
    offset >>= 1;
    __syncthreads();
    if (t < d){ int ai = offset*(2*t+1)-1, bi = offset*(2*t+2)-1;
                int tmp = s[ai]; s[ai] = s[bi]; s[bi] += tmp; }
  }
  __syncthreads();
  if (2*t   < NBLK) bo[2*t]   = s[2*t];
  if (2*t+1 < NBLK) bo[2*t+1] = s[2*t+1];
}
__global__ void k_offs(const int* __restrict__ deg, const int* __restrict__ bo,
                       int* __restrict__ offs, int* __restrict__ cursor){
  __shared__ int s1[256], s2[256];
  int t = threadIdx.x;
  int i = blockIdx.x * 256 + t;
  int v = (i < NATOMS) ? deg[i] : 0;
  s1[t] = v;
  __syncthreads();
  int* rd = s1; int* wr = s2;
  for (int ofs = 1; ofs < 256; ofs <<= 1){
    wr[t] = rd[t] + ((t >= ofs) ? rd[t - ofs] : 0);
    __syncthreads();
    int* tmp = rd; rd = wr; wr = tmp;
  }
  if (i < NATOMS){
    int excl = rd[t] - v + bo[blockIdx.x];
    offs[i] = excl; cursor[i] = excl;
  }
  if (i == 0) offs[NATOMS] = NEDGES;
}
__global__ void k_fill(const int* __restrict__ dsti, int* __restrict__ cursor,
                       int* __restrict__ elist){
  int e = blockIdx.x * 256 + threadIdx.x;
  if (e < NEDGES){ int pos = atomicAdd(&cursor[dsti[e]], 1); elist[pos] = e; }
}
__global__ void k_molstart(const int* __restrict__ atom_mol, int* __restrict__ molst){
  int m = blockIdx.x * 256 + threadIdx.x;
  if (m > NMOLS) return;
  int lo = 0, hi = NATOMS;
  while (lo < hi){ int mid = (lo + hi) >> 1; if (atom_mol[mid] < m) lo = mid + 1; else hi = mid; }
  molst[m] = lo;
}

// ---------------- K=160 GEMM on padded bf16 rows (pitch 192): out = A @ B ----------------
__global__ __launch_bounds__(256) void k_gemm160(
    const ushort* __restrict__ A16, const ushort* __restrict__ Bf,
    ushort* __restrict__ out){
  __shared__ ushort At[64 * 192]; // 24576 B, pitch 384, XOR-swizzled
  const int t = threadIdx.x, w = t >> 6, l = t & 63;
  const long r0 = (long)blockIdx.x * 64;
  const char* Ab = (const char*)(A16 + r0 * 192);
  #pragma unroll
  for (int i = 0; i < 6; i++){
    int dbase = (i * 4 + w) * 1024;
    int d = dbase + l * 16;
    int row = d / 384;
    int sw = (row & 7) << 4;
    gload_lds16(Ab + (d ^ sw), (char*)At + dbase);
  }
  __syncthreads();
  const int lr = l & 15, lg = l >> 4;
  f32x4 acc[4][4] = {};
  for (int kb = 0; kb < 5; kb++){
    s16x8 a[4], b[4];
    #pragma unroll
    for (int m = 0; m < 4; m++){
      int row = m * 16 + lr;
      int cb = (kb * 64 + (lg << 4)) ^ ((row & 7) << 4);
      a[m] = *(const s16x8*)((const char*)At + row * 384 + cb);
    }
    #pragma unroll
    for (int n = 0; n < 4; n++){
      int fi = (w * 4 + n) * 5 + kb;
      b[n] = *(const s16x8*)(Bf + (size_t)(fi * 64 + l) * 8);
    }
    #pragma unroll
    for (int m = 0; m < 4; m++)
      #pragma unroll
      for (int n = 0; n < 4; n++)
        acc[m][n] = mfma16(a[m], b[n], acc[m][n]);
  }
  #pragma unroll
  for (int m = 0; m < 4; m++){
    #pragma unroll
    for (int n = 0; n < 4; n++){
      long base = (r0 + m * 16 + lg * 4) * 256 + (w * 64 + n * 16 + lr);
      #pragma unroll
      for (int r = 0; r < 4; r++)
        out[base + (long)r * 256] = f2bf(acc[m][n][r]);
    }
  }
}

// ---------------- dense E-row GEMM: Y = A @ Whf (gload_lds staging) ----------------
__global__ __launch_bounds__(256) void k_Y(
    const ushort* __restrict__ A, const ushort* __restrict__ Whf,
    ushort* __restrict__ Yout){
  __shared__ ushort At[64 * 256]; // 32KB, pitch 512, XOR-swizzled
  const int t = threadIdx.x, w = t >> 6, l = t & 63;
  const long e0 = (long)blockIdx.x * 64;
  const char* Ab = (const char*)(A + e0 * 256);
  #pragma unroll
  for (int i = 0; i < 8; i++){
    int dbase = (i * 4 + w) * 1024;
    int d = dbase + l * 16;
    int sw = ((d >> 9) & 7) << 4;
    gload_lds16(Ab + (d ^ sw), (char*)At + dbase);
  }
  __syncthreads();
  const int lr = l & 15, lg = l >> 4;
  f32x4 acc[4][4] = {};
  for (int kb = 0; kb < 8; kb++){
    s16x8 a[4], b[4];
    #pragma unroll
    for (int m = 0; m < 4; m++){
      int row = m * 16 + lr;
      int cb = (kb * 64 + (lg << 4)) ^ ((row & 7) << 4);
      a[m] = *(const s16x8*)((const char*)At + row * 512 + cb);
    }
    #pragma unroll
    for (int n = 0; n < 4; n++){
      int fi = (w * 4 + n) * 8 + kb;
      b[n] = *(const s16x8*)(Whf + (size_t)(fi * 64 + l) * 8);
    }
    #pragma unroll
    for (int m = 0; m < 4; m++)
      #pragma unroll
      for (int n = 0; n < 4; n++)
        acc[m][n] = mfma16(a[m], b[n], acc[m][n]);
  }
  #pragma unroll
  for (int m = 0; m < 4; m++){
    #pragma unroll
    for (int n = 0; n < 4; n++){
      long base = (e0 + m * 16 + lg * 4) * 256 + (w * 64 + n * 16 + lr);
      #pragma unroll
      for (int r = 0; r < 4; r++)
        Yout[base + (long)r * 256] = f2bf(acc[m][n][r]);
    }
  }
}

// ---------------- Y with relu applied to A on load (reg-staged) ----------------
__global__ __launch_bounds__(256) void k_Yrelu(
    const ushort* __restrict__ A /* inp16 */, const ushort* __restrict__ Whf,
    ushort* __restrict__ Yout){
  __shared__ ushort At[64 * 256];
  const int t = threadIdx.x, w = t >> 6, l = t & 63;
  const long e0 = (long)blockIdx.x * 64;
  const char* Ab = (const char*)(A + e0 * 256);
  #pragma unroll
  for (int i = 0; i < 8; i++){
    int d = (i * 4 + w) * 1024 + l * 16;
    s16x8 v = *(const s16x8*)(Ab + d);
    #pragma unroll
    for (int j = 0; j < 8; j++){
      ushort u = (ushort)v[j];
      v[j] = (short)((u & 0x8000u) ? 0 : u);
    }
    int sw = ((d >> 9) & 7) << 4;
    *(s16x8*)((char*)At + (d ^ sw)) = v;
  }
  __syncthreads();
  const int lr = l & 15, lg = l >> 4;
  f32x4 acc[4][4] = {};
  for (int kb = 0; kb < 8; kb++){
    s16x8 a[4], b[4];
    #pragma unroll
    for (int m = 0; m < 4; m++){
      int row = m * 16 + lr;
      int cb = (kb * 64 + (lg << 4)) ^ ((row & 7) << 4);
      a[m] = *(const s16x8*)((const char*)At + row * 512 + cb);
    }
    #pragma unroll
    for (int n = 0; n < 4; n++){
      int fi = (w * 4 + n) * 8 + kb;
      b[n] = *(const s16x8*)(Whf + (size_t)(fi * 64 + l) * 8);
    }
    #pragma unroll
    for (int m = 0; m < 4; m++)
      #pragma unroll
      for (int n = 0; n < 4; n++)
        acc[m][n] = mfma16(a[m], b[n], acc[m][n]);
  }
  #pragma unroll
  for (int m = 0; m < 4; m++){
    #pragma unroll
    for (int n = 0; n < 4; n++){
      long base = (e0 + m * 16 + lg * 4) * 256 + (w * 64 + n * 16 + lr);
      #pragma unroll
      for (int r = 0; r < 4; r++)
        Yout[base + (long)r * 256] = f2bf(acc[m][n][r]);
    }
  }
}

// ---------------- fused segsum+combine ----------------
__global__ __launch_bounds__(256) void k_fused(
    const ushort* __restrict__ Y, const ushort* __restrict__ inp16,
    const int* __restrict__ offs, const int* __restrict__ elist,
    ushort* __restrict__ msg_out){
  const int t = threadIdx.x, w = t >> 6, l = t & 63;
  const int a = blockIdx.x * 4 + w;
  const int beg = offs[a], end = offs[a + 1];
  float s0 = 0, s1 = 0, s2 = 0, s3 = 0;
  for (int i = beg; i < end; i++){
    int e = elist[i];
    const ushort4 v = *(const ushort4*)(Y + (size_t)e * 256 + l * 4);
    s0 += bf2f(v.x); s1 += bf2f(v.y); s2 += bf2f(v.z); s3 += bf2f(v.w);
  }
  for (int i = beg; i < end; i++){
    int e = elist[i];
    const ushort4 vy = *(const ushort4*)(Y + (size_t)e * 256 + l * 4);
    long j1 = (long)(e ^ 1);
    const ushort4 vi = *(const ushort4*)(inp16 + j1 * 256 + l * 4);
    ushort4 o;
    float r0 = bf2f(vi.x) + s0 - bf2f(vy.x); o.x = f2bf(r0 > 0.f ? r0 : 0.f);
    float r1 = bf2f(vi.y) + s1 - bf2f(vy.y); o.y = f2bf(r1 > 0.f ? r1 : 0.f);
    float r2 = bf2f(vi.z) + s2 - bf2f(vy.z); o.z = f2bf(r2 > 0.f ? r2 : 0.f);
    float r3 = bf2f(vi.w) + s3 - bf2f(vy.w); o.w = f2bf(r3 > 0.f ? r3 : 0.f);
    *(ushort4*)(msg_out + j1 * 256 + l * 4) = o;
  }
}

// ---------------- segment sum (final) ----------------
__global__ __launch_bounds__(256) void k_segsum(
    const ushort* __restrict__ msg, const int* __restrict__ offs,
    const int* __restrict__ elist, ushort* __restrict__ amsg){
  const int t = threadIdx.x, w = t >> 6, l = t & 63;
  const int a = blockIdx.x * 4 + w;
  const int beg = offs[a], end = offs[a + 1];
  float a0 = 0, a1 = 0, a2 = 0, a3 = 0;
  for (int i = beg; i < end; i++){
    int e = elist[i];
    const ushort4 v = *(const ushort4*)(msg + (size_t)e * 256 + l * 4);
    a0 += bf2f(v.x); a1 += bf2f(v.y); a2 += bf2f(v.z); a3 += bf2f(v.w);
  }
  ushort4 o; o.x = f2bf(a0); o.y = f2bf(a1); o.z = f2bf(a2); o.w = f2bf(a3);
  *(ushort4*)(amsg + (size_t)a * 256 + l * 4) = o;
}

// ---------------- W_o part B: ah = relu(amsg @ Wo2 + partial + b_o) ----------------
__global__ __launch_bounds__(256) void k_woB(
    const ushort* __restrict__ amsg, const ushort* __restrict__ Wof2,
    const ushort* __restrict__ partial, const float* __restrict__ b_o,
    ushort* __restrict__ ah){
  const int t = threadIdx.x, w = t >> 6, l = t & 63, lr = l & 15, lg = l >> 4;
  const long r0 = (long)blockIdx.x * 64;
  f32x4 acc[4][4] = {};
  for (int kb = 0; kb < 8; kb++){
    s16x8 a[4], b[4];
    #pragma unroll
    for (int m = 0; m < 4; m++)
      a[m] = *(const s16x8*)(amsg + (r0 + m * 16 + lr) * 256 + kb * 32 + lg * 8);
    #pragma unroll
    for (int n = 0; n < 4; n++)
      b[n] = *(const s16x8*)(Wof2 + (size_t)(((w * 4 + n) * 8 + kb) * 64 + l) * 8);
    #pragma unroll
    for (int m = 0; m < 4; m++)
      #pragma unroll
      for (int n = 0; n < 4; n++)
        acc[m][n] = mfma16(a[m], b[n], acc[m][n]);
  }
  #pragma unroll
  for (int m = 0; m < 4; m++){
    #pragma unroll
    for (int n = 0; n < 4; n++){
      int col = w * 64 + n * 16 + lr;
      float bo = b_o[col];
      long base = (r0 + m * 16 + lg * 4) * 256 + col;
      #pragma unroll
      for (int r = 0; r < 4; r++){
        long ad = base + (long)r * 256;
        float v = acc[m][n][r] + bf2f(partial[ad]) + bo;
        ah[ad] = f2bf(v > 0.f ? v : 0.f);
      }
    }
  }
}

// ---------------- node head ----------------
__global__ __launch_bounds__(192) void k_node(
    const ushort* __restrict__ ah, const ushort* __restrict__ nWf,
    const float* __restrict__ node_b, float* __restrict__ out_node){
  const int t = threadIdx.x, w = t >> 6, l = t & 63, lr = l & 15, lg = l >> 4;
  const long r0 = (long)blockIdx.x * 64;
  f32x4 acc[4][3] = {};
  for (int kb = 0; kb < 8; kb++){
    s16x8 a[4], b[3];
    #pragma unroll
    for (int m = 0; m < 4; m++)
      a[m] = *(const s16x8*)(ah + (r0 + m * 16 + lr) * 256 + kb * 32 + lg * 8);
    #pragma unroll
    for (int n = 0; n < 3; n++)
      b[n] = *(const s16x8*)(nWf + (size_t)(((w * 3 + n) * 8 + kb) * 64 + l) * 8);
    #pragma unroll
    for (int m = 0; m < 4; m++)
      #pragma unroll
      for (int n = 0; n < 3; n++)
        acc[m][n] = mfma16(a[m], b[n], acc[m][n]);
  }
  #pragma unroll
  for (int m = 0; m < 4; m++){
    #pragma unroll
    for (int n = 0; n < 3; n++){
      int col = (w * 3 + n) * 16 + lr;
      if (col < AF){
        float nb = node_b[col];
        #pragma unroll
        for (int r = 0; r < 4; r++)
          out_node[(r0 + m * 16 + lg * 4 + r) * AF + col] = acc[m][n][r] + nb;
      }
    }
  }
}

// ---------------- edge projection ----------------
__global__ __launch_bounds__(64) void k_proj(
    const ushort* __restrict__ ah, const ushort* __restrict__ eWf,
    float* __restrict__ proj){
  const int l = threadIdx.x, lr = l & 15, lg = l >> 4;
  const long r0 = (long)blockIdx.x * 64;
  f32x4 acc[4] = {};
  for (int kb = 0; kb < 8; kb++){
    s16x8 b = *(const s16x8*)(eWf + (size_t)(kb * 64 + l) * 8);
    #pragma unroll
    for (int m = 0; m < 4; m++){
      s16x8 a = *(const s16x8*)(ah + (r0 + m * 16 + lr) * 256 + kb * 32 + lg * 8);
      acc[m] = mfma16(a, b, acc[m]);
    }
  }
  #pragma unroll
  for (int m = 0; m < 4; m++)
    #pragma unroll
    for (int r = 0; r < 4; r++)
      proj[(r0 + m * 16 + lg * 4 + r) * 16 + lr] = acc[m][r];
}

__global__ void k_edge_out(const int* __restrict__ edge_index, const float* __restrict__ proj,
                           const float* __restrict__ edge_b, float* __restrict__ out_edge){
  int gid = blockIdx.x * 256 + threadIdx.x;
  int i = gid >> 4, c = gid & 15;
  if (c < BFdim){
    int s = edge_index[2 * i];
    int d = edge_index[NEDGES + 2 * i];
    out_edge[(size_t)i * BFdim + c] =
        0.5f * (proj[(size_t)s * 16 + c] + proj[(size_t)d * 16 + c]) + edge_b[c];
  }
}

// ---------------- molecule pooling ----------------
__global__ __launch_bounds__(256) void k_pool(const ushort* __restrict__ ah,
                                              const int* __restrict__ molst,
                                              float* __restrict__ gemb){
  const int t = threadIdx.x, w = t >> 6, l = t & 63;
  const int m = blockIdx.x * 4 + w;
  const int beg = molst[m], end = molst[m + 1];
  float a0 = 0, a1 = 0, a2 = 0, a3 = 0;
  for (int i = beg; i < end; i++){
    const ushort4 v = *(const ushort4*)(ah + (size_t)i * 256 + l * 4);
    a0 += bf2f(v.x); a1 += bf2f(v.y); a2 += bf2f(v.z); a3 += bf2f(v.w);
  }
  f32x4 o = {a0, a1, a2, a3};
  *(f32x4*)(gemb + (size_t)m * 256 + l * 4) = o;
}

// ---------------- graph head (fp32) ----------------
__global__ __launch_bounds__(256) void k_g1(const float* __restrict__ gemb,
                                            const float* __restrict__ gW1,
                                            const float* __restrict__ gb1,
                                            float* __restrict__ ghid){
  __shared__ float s[16 * 256];
  const int t = threadIdx.x;
  const int r0 = blockIdx.x * 16;
  for (int i = 0; i < 16; i++){
    int r = r0 + i;
    s[i * 256 + t] = (r < NMOLS) ? gemb[(size_t)r * 256 + t] : 0.f;
  }
  __syncthreads();
  float acc[16] = {};
  for (int k = 0; k < 256; k++){
    float wv = gW1[(size_t)k * 256 + t];
    #pragma unroll
    for (int i = 0; i < 16; i++) acc[i] += s[i * 256 + k] * wv;
  }
  float b = gb1[t];
  for (int i = 0; i < 16; i++){
    int r = r0 + i;
    if (r < NMOLS){ float v = acc[i] + b; ghid[(size_t)r * 256 + t] = v > 0.f ? v : 0.f; }
  }
}
__global__ void k_g2(const float* __restrict__ ghid, const float* __restrict__ gW2,
                     const float* __restrict__ gb2, float* __restrict__ outg){
  const int t = threadIdx.x, w = t >> 6, l = t & 63;
  const int m = blockIdx.x * 4 + w;
  f32x4 v = *(const f32x4*)(ghid + (size_t)m * 256 + l * 4);
  const f32x4 wv = *(const f32x4*)(gW2 + l * 4);
  float acc = v[0] * wv[0] + v[1] * wv[1] + v[2] * wv[2] + v[3] * wv[3];
  for (int ofs = 32; ofs; ofs >>= 1) acc += __shfl_down(acc, ofs, 64);
  if (l == 0) outg[m] = acc + gb2[0];
}

extern "C" void kernel_launch(void* const* d_in, const int* in_sizes, int n_in,
                              void* d_out, int out_size, void* d_ws, size_t ws_size,
                              hipStream_t stream){
  const float* f_atoms = (const float*)d_in[0];
  const float* f_bonds = (const float*)d_in[1];
  const float* W_i     = (const float*)d_in[2];
  const float* W_h     = (const float*)d_in[3];
  const float* W_o     = (const float*)d_in[4];
  const float* b_o     = (const float*)d_in[5];
  const float* node_W  = (const float*)d_in[6];
  const float* node_b  = (const float*)d_in[7];
  const float* edge_W  = (const float*)d_in[8];
  const float* edge_b  = (const float*)d_in[9];
  const float* g_W1    = (const float*)d_in[10];
  const float* g_b1    = (const float*)d_in[11];
  const float* g_W2    = (const float*)d_in[12];
  const float* g_b2    = (const float*)d_in[13];
  const int* edge_index = (const int*)d_in[14];
  const int* atom_mol   = (const int*)d_in[16];

  float* out_node  = (float*)d_out;
  float* out_edge  = out_node + (size_t)NATOMS * AF;
  float* out_graph = out_edge + (size_t)(NEDGES / 2) * BFdim;

  char* p = (char*)d_ws;
  auto alloc = [&](size_t b) -> char* { char* r = p; p += (b + 255) & ~(size_t)255; return r; };
  ushort* B1 = (ushort*)alloc((size_t)NEDGES * 256 * 2);  // inp16
  ushort* B2 = (ushort*)alloc((size_t)NEDGES * 256 * 2);  // fb16 -> msg1 -> msg2
  ushort* B3 = (ushort*)alloc((size_t)NEDGES * 256 * 2);  // Y0 / Y1 / partial
  ushort* amsg  = (ushort*)alloc((size_t)NATOMS * 256 * 2);
  ushort* ah    = (ushort*)alloc((size_t)NATOMS * 256 * 2); // fa16 -> ah
  float*  proj  = (float*)alloc((size_t)NATOMS * 16 * 4);
  float*  gemb  = (float*)alloc((size_t)NMOLS * 256 * 4);
  float*  ghid  = (float*)alloc((size_t)NMOLS * 256 * 4);
  ushort* Wif   = (ushort*)alloc(160 * 256 * 2);
  ushort* Wof1  = (ushort*)alloc(160 * 256 * 2);
  ushort* Whf   = (ushort*)alloc(256 * 256 * 2);
  ushort* Wof2  = (ushort*)alloc(256 * 256 * 2);
  ushort* nWf   = (ushort*)alloc(256 * 144 * 2);
  ushort* eWf   = (ushort*)alloc(256 * 16 * 2);
  int* deg    = (int*)alloc(NATOMS * 4);
  int* offs   = (int*)alloc((NATOMS + 1) * 4);
  int* cursor = (int*)alloc(NATOMS * 4);
  int* elist  = (int*)alloc(NEDGES * 4);
  int* bsum   = (int*)alloc(1568 * 4);
  int* boff   = (int*)alloc(1568 * 4);
  int* molst  = (int*)alloc((NMOLS + 1) * 4);
  if ((size_t)(p - (char*)d_ws) > ws_size) return;

  ushort* fb16 = B2;            // aliases: dead before k_fused writes msg1
  ushort* fa16 = ah;            // dead before k_woB writes ah

  const int* dsti = edge_index + NEDGES;

  hipMemsetAsync(deg, 0, NATOMS * 4, stream);
  k_prep_weights<<<992, 256, 0, stream>>>(W_i, W_h, W_o, node_W, edge_W,
                                          Wif, Wof1, Whf, Wof2, nWf, eWf);
  k_cvt<<<150000, 256, 0, stream>>>(f_bonds, fb16, NEDGES * 48, BFD);
  k_cvt<<<75000, 256, 0, stream>>>(f_atoms, fa16, NATOMS * 48, AF);
  k_hist<<<3125, 256, 0, stream>>>(dsti, deg);
  k_blocksum<<<NBLK, 256, 0, stream>>>(deg, bsum);
  k_scanblk<<<1, 1024, 0, stream>>>(bsum, boff);
  k_offs<<<NBLK, 256, 0, stream>>>(deg, boff, offs, cursor);
  k_fill<<<3125, 256, 0, stream>>>(dsti, cursor, elist);
  k_molstart<<<51, 256, 0, stream>>>(atom_mol, molst);

  // inp = f_bonds @ W_i -> B1
  k_gemm160<<<12500, 256, 0, stream>>>(fb16, Wif, B1);
  // iter 1: Y0 = relu(inp) @ W_h ; msg1 = relu(inp + segsum(Y0)[src] - Y0[rev])
  k_Yrelu<<<12500, 256, 0, stream>>>(B1, Whf, B3);
  k_fused<<<100000, 256, 0, stream>>>(B3, B1, offs, elist, B2);
  // iter 2
  k_Y<<<12500, 256, 0, stream>>>(B2, Whf, B3);
  k_fused<<<100000, 256, 0, stream>>>(B3, B1, offs, elist, B2);
  // final aggregation
  k_segsum<<<100000, 256, 0, stream>>>(B2, offs, elist, amsg);
  // atom_hiddens = relu(f_atoms @ Wo1 + amsg @ Wo2 + b_o)
  k_gemm160<<<6250, 256, 0, stream>>>(fa16, Wof1, B3);
  k_woB<<<6250, 256, 0, stream>>>(amsg, Wof2, B3, b_o, ah);
  // heads
  k_pool<<<3250, 256, 0, stream>>>(ah, molst, gemb);
  k_node<<<6250, 192, 0, stream>>>(ah, nWf, node_b, out_node);
  k_proj<<<6250, 64, 0, stream>>>(ah, eWf, proj);
  k_edge_out<<<25000, 256, 0, stream>>>(edge_index, proj, edge_b, out_edge);
  k_g1<<<813, 256, 0, stream>>>(gemb, g_W1, g_b1, ghid);
  k_g2<<<3250, 256, 0, stream>>>(ghid, g_W2, g_b2, out_graph);
}